// Round 1
// baseline (5407.122 us; speedup 1.0000x reference)
//
#include <hip/hip_runtime.h>
#include <hip/hip_bf16.h>
#include <cstdint>
#include <cstddef>

typedef short v8s __attribute__((ext_vector_type(8)));
typedef float v4f __attribute__((ext_vector_type(4)));

#define TT 128
#define BB 256
#define HH 1024
#define II 256
#define CC 1000
#define NJ 64      // j-tiles of 16 cols
#define NG 4       // batch groups of 64 rows
#define NSUB 8     // sub-counters per group
#define CSTRIDE 64 // uints between sub-counters (256 B)

__device__ __forceinline__ unsigned short f2bf(float f) {
  unsigned int u = __float_as_uint(f);
  u += 0x7fffu + ((u >> 16) & 1u);   // RTNE
  return (unsigned short)(u >> 16);
}

// Stage 16 rows of W (fp32, row stride K) into LDS in MFMA B-fragment order:
// lds[kk*512 + lane*8 + j] = W[n][kk*32 + quad*8 + j], lane = quad*16 + n.
// Reader (lane n,quad) then does one contiguous 16B ds_read per MFMA.
template <int K>
__device__ __forceinline__ void stage_w(const float* __restrict__ W,
                                        unsigned short* lds, int tid) {
  for (int idx = tid; idx < 16 * K; idx += 256) {
    int n = idx / K;
    int k = idx - n * K;
    unsigned short v = f2bf(W[(size_t)n * K + k]);
    int kk = k >> 5;
    int quad = (k >> 3) & 3;
    int j = k & 7;
    lds[kk * 512 + (quad * 16 + n) * 8 + j] = v;
  }
}

// One recurrent layer. Grid = NJ*NG = 256 blocks (1/CU guaranteed resident),
// block = 256 threads (4 waves). Wave w owns batch rows g*64+w*16..+15,
// block owns output cols j0..j0+15. Per step: out = tanh(bias + in*Wih^T + h*Whh^T).
// Cross-block sync: monotonic sub-counters per batch-group (release/acquire fences).
template <int KIN, bool L0>
__global__ __launch_bounds__(256, 1) void rnn_kernel(
    const float* __restrict__ x, unsigned short* hbuf, unsigned short* h2buf,
    const float* __restrict__ Wih, const float* __restrict__ Whh,
    const float* __restrict__ bih, const float* __restrict__ bhh,
    unsigned int* cnt) {
  __shared__ unsigned short lds_w[16 * (HH + KIN)];  // Whh slice | Wih slice
  const int tid = threadIdx.x;
  const int jt = blockIdx.x & (NJ - 1);
  const int g = blockIdx.x >> 6;
  const int lane = tid & 63;
  const int wave = tid >> 6;
  const int n = lane & 15;
  const int quad = lane >> 4;
  const int j0 = jt * 16;

  stage_w<HH>(Whh + (size_t)j0 * HH, lds_w, tid);
  stage_w<KIN>(Wih + (size_t)j0 * KIN, lds_w + 16 * HH, tid);
  const float bias = bih[j0 + n] + bhh[j0 + n];
  __syncthreads();

  const int arow = g * 64 + wave * 16 + n;        // row this lane loads (A frag)
  const int drow0 = g * 64 + wave * 16 + quad * 4; // rows this lane stores (D frag)
  unsigned int* mycnt = cnt + (g * NSUB + (jt & (NSUB - 1))) * CSTRIDE;

  for (int t = 0; t < TT; ++t) {
    if (t > 0) {  // wait: all 64 blocks of this group finished step t-1
      if (tid == 0) {
        const unsigned int need = (unsigned int)(8 * t);
        for (int s = 0; s < NSUB; ++s) {
          unsigned int* c = cnt + (g * NSUB + s) * CSTRIDE;
          while (__hip_atomic_load(c, __ATOMIC_RELAXED, __HIP_MEMORY_SCOPE_AGENT) < need)
            __builtin_amdgcn_s_sleep(1);
        }
        __threadfence();  // acquire: invalidate L1/L2 so h reads are fresh
      }
      __syncthreads();
    }

    v4f acc = {bias, bias, bias, bias};

    // ---- input contribution ----
    if (L0) {
      const float* xr = x + ((size_t)arow * TT + t) * II + quad * 8;
      #pragma unroll
      for (int kk = 0; kk < II / 32; ++kk) {
        float4 f0 = *(const float4*)(xr + kk * 32);
        float4 f1 = *(const float4*)(xr + kk * 32 + 4);
        v8s a;
        a[0] = (short)f2bf(f0.x); a[1] = (short)f2bf(f0.y);
        a[2] = (short)f2bf(f0.z); a[3] = (short)f2bf(f0.w);
        a[4] = (short)f2bf(f1.x); a[5] = (short)f2bf(f1.y);
        a[6] = (short)f2bf(f1.z); a[7] = (short)f2bf(f1.w);
        v8s b = *(const v8s*)(&lds_w[16 * HH + kk * 512 + lane * 8]);
        acc = __builtin_amdgcn_mfma_f32_16x16x32_bf16(a, b, acc, 0, 0, 0);
      }
    } else {
      const unsigned short* hr = hbuf + ((size_t)(t + 1) * BB + arow) * HH + quad * 8;
      #pragma unroll 8
      for (int kk = 0; kk < HH / 32; ++kk) {
        v8s a = *(const v8s*)(hr + kk * 32);
        v8s b = *(const v8s*)(&lds_w[16 * HH + kk * 512 + lane * 8]);
        acc = __builtin_amdgcn_mfma_f32_16x16x32_bf16(a, b, acc, 0, 0, 0);
      }
    }

    // ---- recurrent contribution (h_{t-1}) ----
    if (t > 0) {
      const unsigned short* hp =
          (L0 ? hbuf + ((size_t)t * BB + arow) * HH
              : h2buf + ((size_t)((t & 1) ^ 1) * BB + arow) * HH) + quad * 8;
      #pragma unroll 8
      for (int kk = 0; kk < HH / 32; ++kk) {
        v8s a = *(const v8s*)(hp + kk * 32);
        v8s b = *(const v8s*)(&lds_w[kk * 512 + lane * 8]);
        acc = __builtin_amdgcn_mfma_f32_16x16x32_bf16(a, b, acc, 0, 0, 0);
      }
    }

    // ---- activation + store h_t ----
    unsigned short* ho = (L0 ? hbuf + (size_t)(t + 1) * BB * HH
                             : h2buf + (size_t)(t & 1) * BB * HH);
    #pragma unroll
    for (int i = 0; i < 4; ++i) {
      float hv = tanhf(acc[i]);
      ho[(size_t)(drow0 + i) * HH + j0 + n] = f2bf(hv);
    }

    __syncthreads();  // drains vmcnt: all block stores complete
    if (tid == 0) {
      __threadfence();  // release: write back L2 so other XCDs see h_t
      __hip_atomic_fetch_add(mycnt, 1u, __ATOMIC_RELAXED, __HIP_MEMORY_SCOPE_AGENT);
    }
  }
}

// out[b][c] = h2_last[b][:] . fcW[c][:] + fcb[c]; M=256, N=1000 (63 tiles), K=1024
__global__ __launch_bounds__(256, 1) void fc_kernel(
    const unsigned short* __restrict__ h2, const float* __restrict__ fcW,
    const float* __restrict__ fcb, float* __restrict__ out) {
  const int tid = threadIdx.x;
  const int ct = blockIdx.x % 63;
  const int g = blockIdx.x / 63;
  const int lane = tid & 63;
  const int wave = tid >> 6;
  const int n = lane & 15;
  const int quad = lane >> 4;
  const int c = ct * 16 + n;
  const int cs = c < CC ? c : CC - 1;
  const float bias = fcb[cs];
  v4f acc = {bias, bias, bias, bias};
  const unsigned short* hr = h2 + (size_t)(g * 64 + wave * 16 + n) * HH + quad * 8;
  const float* wr = fcW + (size_t)cs * HH + quad * 8;
  #pragma unroll 8
  for (int kk = 0; kk < HH / 32; ++kk) {
    v8s a = *(const v8s*)(hr + kk * 32);
    float4 f0 = *(const float4*)(wr + kk * 32);
    float4 f1 = *(const float4*)(wr + kk * 32 + 4);
    v8s b;
    b[0] = (short)f2bf(f0.x); b[1] = (short)f2bf(f0.y);
    b[2] = (short)f2bf(f0.z); b[3] = (short)f2bf(f0.w);
    b[4] = (short)f2bf(f1.x); b[5] = (short)f2bf(f1.y);
    b[6] = (short)f2bf(f1.z); b[7] = (short)f2bf(f1.w);
    acc = __builtin_amdgcn_mfma_f32_16x16x32_bf16(a, b, acc, 0, 0, 0);
  }
  if (c < CC) {
    const int b0 = g * 64 + wave * 16 + quad * 4;
    #pragma unroll
    for (int i = 0; i < 4; ++i) out[(size_t)(b0 + i) * CC + c] = acc[i];
  }
}

extern "C" void kernel_launch(void* const* d_in, const int* in_sizes, int n_in,
                              void* d_out, int out_size, void* d_ws, size_t ws_size,
                              hipStream_t stream) {
  (void)in_sizes; (void)n_in; (void)out_size; (void)ws_size;
  const float* x    = (const float*)d_in[0];
  const float* Wih0 = (const float*)d_in[1];
  const float* Whh0 = (const float*)d_in[2];
  const float* bih0 = (const float*)d_in[3];
  const float* bhh0 = (const float*)d_in[4];
  const float* Wih1 = (const float*)d_in[5];
  const float* Whh1 = (const float*)d_in[6];
  const float* bih1 = (const float*)d_in[7];
  const float* bhh1 = (const float*)d_in[8];
  const float* fcW  = (const float*)d_in[9];
  const float* fcb  = (const float*)d_in[10];

  // ws layout: hbuf (TT+1,BB,HH) bf16 | h2buf (2,BB,HH) bf16 | counters
  unsigned short* hbuf = (unsigned short*)d_ws;
  size_t hbuf_elems = (size_t)(TT + 1) * BB * HH;
  unsigned short* h2buf = hbuf + hbuf_elems;
  unsigned int* cnt = (unsigned int*)(h2buf + (size_t)2 * BB * HH);
  size_t cnt_bytes = (size_t)2 * NG * NSUB * CSTRIDE * sizeof(unsigned int);

  hipMemsetAsync(cnt, 0, cnt_bytes, stream);

  rnn_kernel<II, true><<<NJ * NG, 256, 0, stream>>>(
      x, hbuf, h2buf, Wih0, Whh0, bih0, bhh0, cnt);
  rnn_kernel<HH, false><<<NJ * NG, 256, 0, stream>>>(
      x, hbuf, h2buf, Wih1, Whh1, bih1, bhh1, cnt + (size_t)NG * NSUB * CSTRIDE);
  // t=127 -> parity 1 holds the final hidden state
  fc_kernel<<<63 * NG, 256, 0, stream>>>(
      h2buf + (size_t)1 * BB * HH, fcW, fcb, (float*)d_out);
}

// Round 2
// 1790.356 us; speedup vs baseline: 3.0201x; 3.0201x over previous
//
#include <hip/hip_runtime.h>
#include <hip/hip_bf16.h>
#include <cstdint>
#include <cstddef>

typedef short v8s __attribute__((ext_vector_type(8)));
typedef float v4f __attribute__((ext_vector_type(4)));
typedef float v16f __attribute__((ext_vector_type(16)));

#define TT 128
#define BB 256
#define HH 1024
#define II 256
#define CC 1000

// short-offsets inside the swizzled-weight region of ws
#define OFF_WHH0 0u
#define OFF_WHH1 1048576u
#define OFF_WIH1 2097152u
#define OFF_WIH0 3145728u
#define WSW_SHORTS 3407872u

// LDS: Whh chunks kk=0..55 (56 KB) + acc-exchange scratch (8 KB) = 64 KB
#define LDS_ACC_OFF 57344

__device__ __forceinline__ unsigned short f2bf(float f) {
  unsigned int u = __float_as_uint(f);
  u += 0x7fffu + ((u >> 16) & 1u);  // RTNE
  return (unsigned short)(u >> 16);
}

__device__ __forceinline__ float fast_tanh(float x) {
  float ax = fabsf(x);
  float e = __expf(-2.0f * ax);
  float r = 1.0f - 2.0f * e / (1.0f + e);
  return x < 0.0f ? -r : r;
}

// Pre-swizzle W (fp32 [N][K], N=1024 output cols) into 32x32x16 B-fragment order:
// out[((jt*(K/16) + kk)*64 + lane)*8 + j] = bf16(W[jt*32 + (lane&31)][kk*16 + (lane>>5)*8 + j])
__global__ void swizzle_w(const float* __restrict__ W, unsigned short* __restrict__ out,
                          int K, int total) {
  int idx = blockIdx.x * 256 + threadIdx.x;
  if (idx >= total) return;
  int lane = idx & 63;
  int rest = idx >> 6;
  int KC = K >> 4;
  int kk = rest & (KC - 1);
  int jt = rest / KC;
  int row = jt * 32 + (lane & 31);
  int k0 = kk * 16 + (lane >> 5) * 8;
  const float* src = W + (size_t)row * K + k0;
  float4 f0 = *(const float4*)src;
  float4 f1 = *(const float4*)(src + 4);
  unsigned short o[8] = {f2bf(f0.x), f2bf(f0.y), f2bf(f0.z), f2bf(f0.w),
                         f2bf(f1.x), f2bf(f1.y), f2bf(f1.z), f2bf(f1.w)};
  *(v8s*)(out + (size_t)idx * 8) = *(const v8s*)o;
}

// Fused 2-layer RNN. Grid 256 blocks (1+/CU resident), 256 threads.
// blockIdx&1 = layer; li>>5 = batch group (64 rows); li&31 = 32-col tile.
// Waves: tile = wave&1 (32-row subtile), kh = wave>>1 (0: input matrix, 1: recurrent).
// Exchange: agent-scope atomic stores (write-through), t-indexed buffers read with
// normal loads (fresh addresses -> no stale L2); h2 parity fallback uses agent
// atomic loads. Sync: relaxed agent atomic counters, one per (layer, group).
__global__ __launch_bounds__(256, 1) void rnn_fused(
    const float* __restrict__ x, const unsigned short* __restrict__ wsw,
    const float* __restrict__ bih0, const float* __restrict__ bhh0,
    const float* __restrict__ bih1, const float* __restrict__ bhh1,
    unsigned short* __restrict__ hbuf, unsigned short* __restrict__ h2buf,
    unsigned int* cnt, int h2span) {
  __shared__ unsigned char smem[65536];
  unsigned short* lds_whh = (unsigned short*)smem;
  float* lds_acc = (float*)(smem + LDS_ACC_OFF);

  const int tid = threadIdx.x;
  const int layer = blockIdx.x & 1;
  const int li = blockIdx.x >> 1;
  const int jt = li & 31;
  const int g = li >> 5;
  const int lane = tid & 63;
  const int wave = tid >> 6;
  const int tile = wave & 1;
  const int kh = wave >> 1;
  const int col = lane & 31;
  const int half = lane >> 5;
  const int koff = half * 8;
  const int j0 = jt * 32;

  const unsigned short* whh_tile = wsw + (size_t)layer * OFF_WHH1 + (size_t)jt * 32768;
  const unsigned short* wih_tile = layer ? (wsw + OFF_WIH1 + (size_t)jt * 32768)
                                         : (wsw + OFF_WIH0 + (size_t)jt * 8192);

  // stage Whh chunks 0..55 into LDS (contiguous copy, already fragment-ordered)
  for (int i = tid * 8; i < 56 * 512; i += 2048)
    *(v8s*)(lds_whh + i) = *(const v8s*)(whh_tile + i);

  const float bias = layer ? (bih1[j0 + col] + bhh1[j0 + col])
                           : (bih0[j0 + col] + bhh0[j0 + col]);
  __syncthreads();

  const int arow = g * 64 + tile * 32 + col;
  unsigned int* cnt0 = cnt + g * 64;
  unsigned int* cnt1 = cnt + 256 + g * 64;
  unsigned int* mycnt = layer ? cnt1 : cnt0;
  const bool big = (h2span != 2);

  for (int t = 0; t < TT; ++t) {
    // ---- inter-block wait (no cache fences; fresh-address discipline) ----
    if (tid == 0) {
      if (layer == 0) {
        if (t > 0) {
          unsigned int need = 32u * t;
          while (__hip_atomic_load(cnt0, __ATOMIC_RELAXED, __HIP_MEMORY_SCOPE_AGENT) < need)
            __builtin_amdgcn_s_sleep(1);
        }
      } else {
        unsigned int need0 = 32u * (t + 1);
        while (__hip_atomic_load(cnt0, __ATOMIC_RELAXED, __HIP_MEMORY_SCOPE_AGENT) < need0)
          __builtin_amdgcn_s_sleep(1);
        if (t > 0) {
          unsigned int need1 = 32u * t;
          while (__hip_atomic_load(cnt1, __ATOMIC_RELAXED, __HIP_MEMORY_SCOPE_AGENT) < need1)
            __builtin_amdgcn_s_sleep(1);
        }
      }
    }
    __syncthreads();

    v16f acc = {};
    if (kh == 0) {
      #pragma unroll
      for (int r = 0; r < 16; ++r) acc[r] = bias;
    }

    if (layer == 0) {
      if (kh == 0) {
        // x @ Wih0^T  (K=256, 16 chunks, B-frags from L2-hot global)
        const float* xr = x + ((size_t)arow * TT + t) * II + koff;
        #pragma unroll 4
        for (int kk = 0; kk < 16; ++kk) {
          float4 f0 = *(const float4*)(xr + kk * 16);
          float4 f1 = *(const float4*)(xr + kk * 16 + 4);
          unsigned short o[8] = {f2bf(f0.x), f2bf(f0.y), f2bf(f0.z), f2bf(f0.w),
                                 f2bf(f1.x), f2bf(f1.y), f2bf(f1.z), f2bf(f1.w)};
          v8s b = *(const v8s*)(wih_tile + ((size_t)kk * 64 + lane) * 8);
          acc = __builtin_amdgcn_mfma_f32_32x32x16_bf16(*(const v8s*)o, b, acc, 0, 0, 0);
        }
        if (t > 0) {  // recurrent chunks 0..23 (LDS B-frags)
          const unsigned short* hr = hbuf + ((size_t)t * BB + arow) * HH + koff;
          #pragma unroll 8
          for (int kk = 0; kk < 24; ++kk) {
            v8s a = *(const v8s*)(hr + kk * 16);
            v8s b = *(const v8s*)(lds_whh + ((size_t)kk * 64 + lane) * 8);
            acc = __builtin_amdgcn_mfma_f32_32x32x16_bf16(a, b, acc, 0, 0, 0);
          }
        }
      } else if (t > 0) {  // recurrent chunks 24..63
        const unsigned short* hr = hbuf + ((size_t)t * BB + arow) * HH + koff;
        #pragma unroll 8
        for (int kk = 24; kk < 56; ++kk) {
          v8s a = *(const v8s*)(hr + kk * 16);
          v8s b = *(const v8s*)(lds_whh + ((size_t)kk * 64 + lane) * 8);
          acc = __builtin_amdgcn_mfma_f32_32x32x16_bf16(a, b, acc, 0, 0, 0);
        }
        #pragma unroll
        for (int kk = 56; kk < 64; ++kk) {
          v8s a = *(const v8s*)(hr + kk * 16);
          v8s b = *(const v8s*)(whh_tile + ((size_t)kk * 64 + lane) * 8);
          acc = __builtin_amdgcn_mfma_f32_32x32x16_bf16(a, b, acc, 0, 0, 0);
        }
      }
    } else {
      if (kh == 0) {
        // h1[t] @ Wih1^T (h1 ready per cnt0 >= 32(t+1); fresh t-indexed address)
        const unsigned short* hr = hbuf + ((size_t)(t + 1) * BB + arow) * HH + koff;
        #pragma unroll 8
        for (int kk = 0; kk < 64; ++kk) {
          v8s a = *(const v8s*)(hr + kk * 16);
          v8s b = *(const v8s*)(wih_tile + ((size_t)kk * 64 + lane) * 8);
          acc = __builtin_amdgcn_mfma_f32_32x32x16_bf16(a, b, acc, 0, 0, 0);
        }
      } else if (t > 0) {
        const int slot_r = big ? (t - 1) : ((t - 1) & 1);
        const unsigned short* hr = h2buf + ((size_t)slot_r * BB + arow) * HH + koff;
        if (big) {
          #pragma unroll 8
          for (int kk = 0; kk < 56; ++kk) {
            v8s a = *(const v8s*)(hr + kk * 16);
            v8s b = *(const v8s*)(lds_whh + ((size_t)kk * 64 + lane) * 8);
            acc = __builtin_amdgcn_mfma_f32_32x32x16_bf16(a, b, acc, 0, 0, 0);
          }
          #pragma unroll
          for (int kk = 56; kk < 64; ++kk) {
            v8s a = *(const v8s*)(hr + kk * 16);
            v8s b = *(const v8s*)(whh_tile + ((size_t)kk * 64 + lane) * 8);
            acc = __builtin_amdgcn_mfma_f32_32x32x16_bf16(a, b, acc, 0, 0, 0);
          }
        } else {
          #pragma unroll 8
          for (int kk = 0; kk < 64; ++kk) {
            const unsigned long long* p = (const unsigned long long*)(hr + kk * 16);
            unsigned long long lo = __hip_atomic_load(p, __ATOMIC_RELAXED, __HIP_MEMORY_SCOPE_AGENT);
            unsigned long long hi = __hip_atomic_load(p + 1, __ATOMIC_RELAXED, __HIP_MEMORY_SCOPE_AGENT);
            union { unsigned long long q[2]; v8s v; } u;
            u.q[0] = lo; u.q[1] = hi;
            v8s b = (kk < 56) ? *(const v8s*)(lds_whh + ((size_t)kk * 64 + lane) * 8)
                              : *(const v8s*)(whh_tile + ((size_t)kk * 64 + lane) * 8);
            acc = __builtin_amdgcn_mfma_f32_32x32x16_bf16(u.v, b, acc, 0, 0, 0);
          }
        }
      }
    }

    // ---- cross-wave K reduction through LDS ----
    if (kh == 1) {
      float* dst = lds_acc + tile * 1024 + lane * 16;
      #pragma unroll
      for (int r4 = 0; r4 < 4; ++r4)
        *(float4*)(dst + r4 * 4) =
            make_float4(acc[r4 * 4 + 0], acc[r4 * 4 + 1], acc[r4 * 4 + 2], acc[r4 * 4 + 3]);
    }
    __syncthreads();

    if (kh == 0) {
      const float* srcp = lds_acc + tile * 1024 + lane * 16;
      unsigned short* hout = layer ? h2buf + (size_t)(big ? t : (t & 1)) * BB * HH
                                   : hbuf + (size_t)(t + 1) * BB * HH;
      const int rowbase = g * 64 + tile * 32;
      #pragma unroll
      for (int r = 0; r < 16; ++r) {
        float v = acc[r] + srcp[r];
        float th = fast_tanh(v);
        int row = (r & 3) + 8 * (r >> 2) + 4 * half;
        __hip_atomic_store(hout + (size_t)(rowbase + row) * HH + j0 + col, f2bf(th),
                           __ATOMIC_RELAXED, __HIP_MEMORY_SCOPE_AGENT);
      }
    }
    asm volatile("s_waitcnt vmcnt(0)" ::: "memory");
    __syncthreads();
    if (tid == 0)
      __hip_atomic_fetch_add(mycnt, 1u, __ATOMIC_RELAXED, __HIP_MEMORY_SCOPE_AGENT);
  }
}

// out[b][c] = h2_last[b][:] . fcW[c][:] + fcb[c]; 16x16x32 path (round-0 verified)
__global__ __launch_bounds__(256, 1) void fc_kernel(
    const unsigned short* __restrict__ h2, const float* __restrict__ fcW,
    const float* __restrict__ fcb, float* __restrict__ out) {
  const int tid = threadIdx.x;
  const int ct = blockIdx.x % 63;
  const int g = blockIdx.x / 63;
  const int lane = tid & 63;
  const int wave = tid >> 6;
  const int n = lane & 15;
  const int quad = lane >> 4;
  const int c = ct * 16 + n;
  const int cs = c < CC ? c : CC - 1;
  const float bias = fcb[cs];
  v4f acc = {bias, bias, bias, bias};
  const unsigned short* hr = h2 + (size_t)(g * 64 + wave * 16 + n) * HH + quad * 8;
  const float* wr = fcW + (size_t)cs * HH + quad * 8;
  #pragma unroll 8
  for (int kk = 0; kk < HH / 32; ++kk) {
    v8s a = *(const v8s*)(hr + kk * 32);
    float4 f0 = *(const float4*)(wr + kk * 32);
    float4 f1 = *(const float4*)(wr + kk * 32 + 4);
    v8s b;
    b[0] = (short)f2bf(f0.x); b[1] = (short)f2bf(f0.y);
    b[2] = (short)f2bf(f0.z); b[3] = (short)f2bf(f0.w);
    b[4] = (short)f2bf(f1.x); b[5] = (short)f2bf(f1.y);
    b[6] = (short)f2bf(f1.z); b[7] = (short)f2bf(f1.w);
    acc = __builtin_amdgcn_mfma_f32_16x16x32_bf16(a, b, acc, 0, 0, 0);
  }
  if (c < CC) {
    const int b0 = g * 64 + wave * 16 + quad * 4;
    #pragma unroll
    for (int i = 0; i < 4; ++i) out[(size_t)(b0 + i) * CC + c] = acc[i];
  }
}

extern "C" void kernel_launch(void* const* d_in, const int* in_sizes, int n_in,
                              void* d_out, int out_size, void* d_ws, size_t ws_size,
                              hipStream_t stream) {
  (void)in_sizes; (void)n_in; (void)out_size;
  const float* x    = (const float*)d_in[0];
  const float* Wih0 = (const float*)d_in[1];
  const float* Whh0 = (const float*)d_in[2];
  const float* bih0 = (const float*)d_in[3];
  const float* bhh0 = (const float*)d_in[4];
  const float* Wih1 = (const float*)d_in[5];
  const float* Whh1 = (const float*)d_in[6];
  const float* bih1 = (const float*)d_in[7];
  const float* bhh1 = (const float*)d_in[8];
  const float* fcW  = (const float*)d_in[9];
  const float* fcb  = (const float*)d_in[10];

  // ws layout: swizzled weights | hbuf (129 slots) | h2buf (128 or 2 slots) | counters
  unsigned short* wsw = (unsigned short*)d_ws;
  unsigned short* hbuf = wsw + WSW_SHORTS;
  unsigned short* h2buf = hbuf + (size_t)(TT + 1) * BB * HH;

  const size_t base_bytes = (size_t)WSW_SHORTS * 2 + (size_t)(TT + 1) * BB * HH * 2;
  const size_t big_bytes = base_bytes + (size_t)TT * BB * HH * 2 + 2048;
  const bool big = (ws_size >= big_bytes);
  const int h2span = big ? TT : 2;
  unsigned int* cnt = (unsigned int*)(h2buf + (size_t)h2span * BB * HH);

  hipMemsetAsync(cnt, 0, 2048, stream);
  swizzle_w<<<512, 256, 0, stream>>>(Whh0, wsw + OFF_WHH0, HH, 32 * 64 * 64);
  swizzle_w<<<512, 256, 0, stream>>>(Whh1, wsw + OFF_WHH1, HH, 32 * 64 * 64);
  swizzle_w<<<512, 256, 0, stream>>>(Wih1, wsw + OFF_WIH1, HH, 32 * 64 * 64);
  swizzle_w<<<128, 256, 0, stream>>>(Wih0, wsw + OFF_WIH0, II, 32 * 16 * 64);

  rnn_fused<<<256, 256, 0, stream>>>(x, wsw, bih0, bhh0, bih1, bhh1,
                                     hbuf, h2buf, cnt, h2span);

  const unsigned short* h2last = h2buf + (size_t)(big ? (TT - 1) : 1) * BB * HH;
  fc_kernel<<<63 * 4, 256, 0, stream>>>(h2last, fcW, fcb, (float*)d_out);
}

// Round 3
// 1746.887 us; speedup vs baseline: 3.0953x; 1.0249x over previous
//
#include <hip/hip_runtime.h>
#include <hip/hip_bf16.h>
#include <cstdint>
#include <cstddef>

typedef short v8s __attribute__((ext_vector_type(8)));
typedef float v4f __attribute__((ext_vector_type(4)));
typedef float v16f __attribute__((ext_vector_type(16)));

#define TT 128
#define BB 256
#define HH 1024
#define II 256
#define CC 1000

// short-offsets inside the swizzled-weight region of ws
#define OFF_WHH0 0u
#define OFF_WHH1 1048576u
#define OFF_WIH1 2097152u
#define OFF_WIH0 3145728u
#define WSW_SHORTS 3407872u

#define LDS_ACC_OFF 57344   // Whh chunks 0..55 (56KB) | acc exchange (8KB)
#define NJB 32
#define FLAG_UINTS (8 * (TT + 1) * NJB)
#define FLAG_BYTES (FLAG_UINTS * 4)

__device__ __forceinline__ unsigned short f2bf(float f) {
  unsigned int u = __float_as_uint(f);
  u += 0x7fffu + ((u >> 16) & 1u);  // RTNE
  return (unsigned short)(u >> 16);
}

__device__ __forceinline__ float fast_tanh(float x) {
  float ax = fabsf(x);
  float e = __expf(-2.0f * ax);
  float r = 1.0f - 2.0f * e / (1.0f + e);
  return x < 0.0f ? -r : r;
}

__device__ __forceinline__ v16f mfma32(v8s a, v8s b, v16f c) {
  return __builtin_amdgcn_mfma_f32_32x32x16_bf16(a, b, c, 0, 0, 0);
}

// Pre-swizzle W (fp32 [N][K]) into 32x32x16 B-fragment order:
// out[((jt*(K/16)+kk)*64+lane)*8+j] = bf16(W[jt*32+(lane&31)][kk*16+(lane>>5)*8+j])
__global__ void swizzle_w(const float* __restrict__ W, unsigned short* __restrict__ out,
                          int K, int total) {
  int idx = blockIdx.x * 256 + threadIdx.x;
  if (idx >= total) return;
  int lane = idx & 63;
  int rest = idx >> 6;
  int KC = K >> 4;
  int kk = rest & (KC - 1);
  int jt = rest / KC;
  int row = jt * 32 + (lane & 31);
  int k0 = kk * 16 + (lane >> 5) * 8;
  const float* src = W + (size_t)row * K + k0;
  float4 f0 = *(const float4*)src;
  float4 f1 = *(const float4*)(src + 4);
  unsigned short o[8] = {f2bf(f0.x), f2bf(f0.y), f2bf(f0.z), f2bf(f0.w),
                         f2bf(f1.x), f2bf(f1.y), f2bf(f1.z), f2bf(f1.w)};
  *(v8s*)(out + (size_t)idx * 8) = *(const v8s*)o;
}

// Gated 16-producer-tile MFMA accumulate. Tiles j=0..15 -> chunks kk=kh*32+2j,+1.
// Flags vector-polled (one round trip); all-ready fast path is a clean unrolled loop.
template <bool USE_LDS, bool ATOMIC_A>
__device__ __forceinline__ v16f gated16(v16f acc, const unsigned int* flg, int kh,
                                        int lane, const unsigned short* hr,
                                        const unsigned short* ldsb,
                                        const unsigned short* globb) {
  const unsigned int* fp = flg + kh * 16 + (lane & 15);
  unsigned int fv = __hip_atomic_load(fp, __ATOMIC_RELAXED, __HIP_MEMORY_SCOPE_AGENT);
  unsigned int mask = (unsigned int)(__ballot(fv != 0) & 0xFFFFull);

  auto afrag = [&](int kk) -> v8s {
    if (ATOMIC_A) {
      const unsigned long long* p = (const unsigned long long*)(hr + kk * 16);
      unsigned long long lo = __hip_atomic_load(p, __ATOMIC_RELAXED, __HIP_MEMORY_SCOPE_AGENT);
      unsigned long long hi = __hip_atomic_load(p + 1, __ATOMIC_RELAXED, __HIP_MEMORY_SCOPE_AGENT);
      union { unsigned long long q[2]; v8s v; } u;
      u.q[0] = lo; u.q[1] = hi;
      return u.v;
    }
    return *(const v8s*)(hr + kk * 16);
  };
  auto bfrag = [&](int kk) -> v8s {
    if (USE_LDS && kk < 56) return *(const v8s*)(ldsb + ((size_t)kk * 64 + lane) * 8);
    return *(const v8s*)(globb + ((size_t)kk * 64 + lane) * 8);
  };

  if (mask == 0xFFFFu) {
    #pragma unroll 4
    for (int j = 0; j < 16; ++j) {
      int kk = kh * 32 + 2 * j;
      acc = mfma32(afrag(kk), bfrag(kk), acc);
      acc = mfma32(afrag(kk + 1), bfrag(kk + 1), acc);
    }
  } else {
    unsigned int done = 0;
    while (true) {
      unsigned int newr = mask & ~done;
      while (newr) {
        int j = __builtin_ctz(newr);
        newr &= newr - 1;
        int kk = kh * 32 + 2 * j;
        acc = mfma32(afrag(kk), bfrag(kk), acc);
        acc = mfma32(afrag(kk + 1), bfrag(kk + 1), acc);
      }
      done |= mask;
      if (done == 0xFFFFu) break;
      __builtin_amdgcn_s_sleep(1);
      fv = __hip_atomic_load(fp, __ATOMIC_RELAXED, __HIP_MEMORY_SCOPE_AGENT);
      mask = (unsigned int)(__ballot(fv != 0) & 0xFFFFull);
    }
  }
  asm volatile("" ::: "memory");  // keep later code from moving above the gate
  return acc;
}

// Fused 2-layer RNN, fine-grained dataflow. Grid 256 blocks, 256 threads.
// blockIdx%8 = l*4+g (one XCD per (layer,group) -> L2-shared h/x/weights),
// jt = blockIdx>>3 (32-col tile). Waves: tile = wave&1 (32 rows), kh = wave>>1 (K half).
__global__ __launch_bounds__(256, 1) void rnn_fused(
    const float* __restrict__ x, const unsigned short* __restrict__ wsw,
    const float* __restrict__ bih0, const float* __restrict__ bhh0,
    const float* __restrict__ bih1, const float* __restrict__ bhh1,
    unsigned short* __restrict__ hbuf, unsigned short* __restrict__ h2buf,
    unsigned int* flags, int h2span) {
  __shared__ unsigned char smem[65536];
  unsigned short* lds_whh = (unsigned short*)smem;
  float* lds_acc = (float*)(smem + LDS_ACC_OFF);

  const int tid = threadIdx.x;
  const int xsel = blockIdx.x & 7;
  const int layer = xsel >> 2;
  const int g = xsel & 3;
  const int jt = blockIdx.x >> 3;
  const int lane = tid & 63;
  const int wave = tid >> 6;
  const int tile = wave & 1;
  const int kh = wave >> 1;
  const int col = lane & 31;
  const int half = lane >> 5;
  const int koff = half * 8;
  const int j0 = jt * 32;

  const unsigned short* whh_tile = wsw + (size_t)layer * OFF_WHH1 + (size_t)jt * 32768;
  const unsigned short* wih_tile = layer ? (wsw + OFF_WIH1 + (size_t)jt * 32768)
                                         : (wsw + OFF_WIH0 + (size_t)jt * 8192);

  for (int i = tid * 8; i < 56 * 512; i += 2048)
    *(v8s*)(lds_whh + i) = *(const v8s*)(whh_tile + i);

  const float bias = layer ? (bih1[j0 + col] + bhh1[j0 + col])
                           : (bih0[j0 + col] + bhh0[j0 + col]);
  __syncthreads();

  const int arow = g * 64 + tile * 32 + col;
  const int rowbase = g * 64 + tile * 32;
  unsigned int* flbase = flags + (size_t)xsel * (TT + 1) * NJB;
  unsigned int* fl0base = flags + (size_t)g * (TT + 1) * NJB;
  const bool big = (h2span != 2);

  for (int t = 0; t < TT; ++t) {
    v16f acc = {};
    if (kh == 0) {
      #pragma unroll
      for (int r = 0; r < 16; ++r) acc[r] = bias;
    }

    // ---- input term ----
    if (layer == 0) {
      const float* xr = x + ((size_t)arow * TT + t) * II + koff;
      #pragma unroll 2
      for (int kk = kh * 8; kk < kh * 8 + 8; ++kk) {
        float4 f0 = *(const float4*)(xr + kk * 16);
        float4 f1 = *(const float4*)(xr + kk * 16 + 4);
        unsigned short o[8] = {f2bf(f0.x), f2bf(f0.y), f2bf(f0.z), f2bf(f0.w),
                               f2bf(f1.x), f2bf(f1.y), f2bf(f1.z), f2bf(f1.w)};
        v8s b = *(const v8s*)(wih_tile + ((size_t)kk * 64 + lane) * 8);
        acc = mfma32(*(const v8s*)o, b, acc);
      }
    } else {
      // h1[t] @ Wih1^T, gated on layer0 flags slot t+1 (layer0 runs ahead)
      const unsigned short* hr = hbuf + ((size_t)(t + 1) * BB + arow) * HH + koff;
      acc = gated16<false, false>(acc, fl0base + (size_t)(t + 1) * NJB, kh, lane,
                                  hr, nullptr, wih_tile);
    }

    // ---- recurrent term ----
    if (t > 0) {
      if (layer == 0) {
        const unsigned short* hr = hbuf + ((size_t)t * BB + arow) * HH + koff;
        acc = gated16<true, false>(acc, flbase + (size_t)t * NJB, kh, lane,
                                   hr, lds_whh, whh_tile);
      } else {
        const int slot_r = big ? (t - 1) : ((t - 1) & 1);
        const unsigned short* hr = h2buf + ((size_t)slot_r * BB + arow) * HH + koff;
        if (big)
          acc = gated16<true, false>(acc, flbase + (size_t)(t - 1) * NJB, kh, lane,
                                     hr, lds_whh, whh_tile);
        else
          acc = gated16<true, true>(acc, flbase + (size_t)(t - 1) * NJB, kh, lane,
                                    hr, lds_whh, whh_tile);
      }
    }

    // ---- cross-wave K reduction (conflict-free: 16B lane stride) ----
    if (kh == 1) {
      float* dst = lds_acc + tile * 1024;
      #pragma unroll
      for (int r4 = 0; r4 < 4; ++r4)
        *(float4*)(dst + r4 * 256 + lane * 4) =
            make_float4(acc[r4 * 4 + 0], acc[r4 * 4 + 1], acc[r4 * 4 + 2], acc[r4 * 4 + 3]);
    }
    __syncthreads();

    if (kh == 0) {
      const float* srcp = lds_acc + tile * 1024;
      unsigned short* hout = layer ? h2buf + (size_t)(big ? t : (t & 1)) * BB * HH
                                   : hbuf + (size_t)(t + 1) * BB * HH;
      #pragma unroll
      for (int r4 = 0; r4 < 4; ++r4) {
        float4 part = *(const float4*)(srcp + r4 * 256 + lane * 4);
        float pv[4] = {part.x, part.y, part.z, part.w};
        #pragma unroll
        for (int q = 0; q < 4; ++q) {
          int r = r4 * 4 + q;
          float th = fast_tanh(acc[r] + pv[q]);
          int row = (r & 3) + 8 * (r >> 2) + 4 * half;
          __hip_atomic_store(hout + (size_t)(rowbase + row) * HH + j0 + col, f2bf(th),
                             __ATOMIC_RELAXED, __HIP_MEMORY_SCOPE_AGENT);
        }
      }
    }
    asm volatile("s_waitcnt vmcnt(0)" ::: "memory");
    __syncthreads();
    if (tid == 0) {
      int slot_w = layer ? t : (t + 1);
      __hip_atomic_store(flbase + (size_t)slot_w * NJB + jt, 1u,
                         __ATOMIC_RELAXED, __HIP_MEMORY_SCOPE_AGENT);
    }
  }
}

// out[b][c] = h2_last[b][:] . fcW[c][:] + fcb[c]
__global__ __launch_bounds__(256, 1) void fc_kernel(
    const unsigned short* __restrict__ h2, const float* __restrict__ fcW,
    const float* __restrict__ fcb, float* __restrict__ out, int atomic_a) {
  const int tid = threadIdx.x;
  const int ct = blockIdx.x % 63;
  const int g = blockIdx.x / 63;
  const int lane = tid & 63;
  const int wave = tid >> 6;
  const int n = lane & 15;
  const int quad = lane >> 4;
  const int c = ct * 16 + n;
  const int cs = c < CC ? c : CC - 1;
  const float bias = fcb[cs];
  v4f acc = {bias, bias, bias, bias};
  const unsigned short* hr = h2 + (size_t)(g * 64 + wave * 16 + n) * HH + quad * 8;
  const float* wr = fcW + (size_t)cs * HH + quad * 8;
  #pragma unroll 8
  for (int kk = 0; kk < HH / 32; ++kk) {
    v8s a;
    if (atomic_a) {
      const unsigned long long* p = (const unsigned long long*)(hr + kk * 32);
      unsigned long long lo = __hip_atomic_load(p, __ATOMIC_RELAXED, __HIP_MEMORY_SCOPE_AGENT);
      unsigned long long hi = __hip_atomic_load(p + 1, __ATOMIC_RELAXED, __HIP_MEMORY_SCOPE_AGENT);
      union { unsigned long long q[2]; v8s v; } u;
      u.q[0] = lo; u.q[1] = hi;
      a = u.v;
    } else {
      a = *(const v8s*)(hr + kk * 32);
    }
    float4 f0 = *(const float4*)(wr + kk * 32);
    float4 f1 = *(const float4*)(wr + kk * 32 + 4);
    v8s b;
    b[0] = (short)f2bf(f0.x); b[1] = (short)f2bf(f0.y);
    b[2] = (short)f2bf(f0.z); b[3] = (short)f2bf(f0.w);
    b[4] = (short)f2bf(f1.x); b[5] = (short)f2bf(f1.y);
    b[6] = (short)f2bf(f1.z); b[7] = (short)f2bf(f1.w);
    acc = __builtin_amdgcn_mfma_f32_16x16x32_bf16(a, b, acc, 0, 0, 0);
  }
  if (c < CC) {
    const int b0 = g * 64 + wave * 16 + quad * 4;
    #pragma unroll
    for (int i = 0; i < 4; ++i) out[(size_t)(b0 + i) * CC + c] = acc[i];
  }
}

extern "C" void kernel_launch(void* const* d_in, const int* in_sizes, int n_in,
                              void* d_out, int out_size, void* d_ws, size_t ws_size,
                              hipStream_t stream) {
  (void)in_sizes; (void)n_in; (void)out_size;
  const float* x    = (const float*)d_in[0];
  const float* Wih0 = (const float*)d_in[1];
  const float* Whh0 = (const float*)d_in[2];
  const float* bih0 = (const float*)d_in[3];
  const float* bhh0 = (const float*)d_in[4];
  const float* Wih1 = (const float*)d_in[5];
  const float* Whh1 = (const float*)d_in[6];
  const float* bih1 = (const float*)d_in[7];
  const float* bhh1 = (const float*)d_in[8];
  const float* fcW  = (const float*)d_in[9];
  const float* fcb  = (const float*)d_in[10];

  // ws layout: swizzled weights | hbuf (129 slots) | h2buf (128 or 2 slots) | flags
  unsigned short* wsw = (unsigned short*)d_ws;
  unsigned short* hbuf = wsw + WSW_SHORTS;
  unsigned short* h2buf = hbuf + (size_t)(TT + 1) * BB * HH;

  const size_t big_bytes = (size_t)WSW_SHORTS * 2 + (size_t)(TT + 1) * BB * HH * 2 +
                           (size_t)TT * BB * HH * 2 + FLAG_BYTES;
  const bool big = (ws_size >= big_bytes);
  const int h2span = big ? TT : 2;
  unsigned int* flags = (unsigned int*)(h2buf + (size_t)h2span * BB * HH);

  hipMemsetAsync(flags, 0, FLAG_BYTES, stream);
  swizzle_w<<<512, 256, 0, stream>>>(Whh0, wsw + OFF_WHH0, HH, 32 * 64 * 64);
  swizzle_w<<<512, 256, 0, stream>>>(Whh1, wsw + OFF_WHH1, HH, 32 * 64 * 64);
  swizzle_w<<<512, 256, 0, stream>>>(Wih1, wsw + OFF_WIH1, HH, 32 * 64 * 64);
  swizzle_w<<<128, 256, 0, stream>>>(Wih0, wsw + OFF_WIH0, II, 32 * 16 * 64);

  rnn_fused<<<256, 256, 0, stream>>>(x, wsw, bih0, bhh0, bih1, bhh1,
                                     hbuf, h2buf, flags, h2span);

  const unsigned short* h2last = h2buf + (size_t)(big ? (TT - 1) : 1) * BB * HH;
  fc_kernel<<<63 * 4, 256, 0, stream>>>(h2last, fcW, fcb, (float*)d_out, big ? 0 : 1);
}